// Round 1
// baseline (883.627 us; speedup 1.0000x reference)
//
#include <hip/hip_runtime.h>

// Problem: l=32, m=4096, n=512 fp32.
//   x = (input - min(input)) / (max(input) - min(input))
//   w[...,0] = 1; w[...,k] = w[...,k-1] + a/w[...,k-1] - b*x[...,k-1]
// Rows (l*m = 131072) are independent; n is strictly sequential.
//
// Numerics: recurrence is chaotic near w->0 crossings; we replicate numpy's
// fp32 op order exactly (IEEE div, no fp contraction) for bit-exactness.

#define ROWS 131072
#define NCOL 512
#define NV4  (NCOL / 4)   // 128 float4 per row

__device__ __forceinline__ unsigned f2key(float f) {
    unsigned u = __float_as_uint(f);
    return (u & 0x80000000u) ? ~u : (u | 0x80000000u);  // monotone float->uint
}
__device__ __forceinline__ float key2f(unsigned k) {
    unsigned u = (k & 0x80000000u) ? (k & 0x7fffffffu) : ~k;
    return __uint_as_float(u);
}

__global__ void init_ws_kernel(unsigned* ws) {
    ws[0] = 0xFFFFFFFFu;  // min key accumulator
    ws[1] = 0u;           // max key accumulator
}

__global__ __launch_bounds__(256) void minmax_kernel(
        const float4* __restrict__ in, unsigned* __restrict__ ws, int n4) {
    unsigned mnk = 0xFFFFFFFFu, mxk = 0u;
    int idx = blockIdx.x * blockDim.x + threadIdx.x;
    int stride = gridDim.x * blockDim.x;
    for (int i = idx; i < n4; i += stride) {
        float4 v = in[i];
        unsigned k0 = f2key(v.x), k1 = f2key(v.y), k2 = f2key(v.z), k3 = f2key(v.w);
        mnk = min(mnk, min(min(k0, k1), min(k2, k3)));
        mxk = max(mxk, max(max(k0, k1), max(k2, k3)));
    }
    // wave(64) shuffle reduction
    for (int off = 32; off; off >>= 1) {
        mnk = min(mnk, (unsigned)__shfl_down((int)mnk, off));
        mxk = max(mxk, (unsigned)__shfl_down((int)mxk, off));
    }
    if ((threadIdx.x & 63) == 0) {
        atomicMin(&ws[0], mnk);
        atomicMax(&ws[1], mxk);
    }
}

__global__ __launch_bounds__(256) void recur_kernel(
        const float* __restrict__ in,
        const float* __restrict__ alpha,
        const float* __restrict__ beta,
        const unsigned* __restrict__ ws,
        float* __restrict__ out) {
    #pragma clang fp contract(off)   // bit-exact vs numpy: no fma fusion
    const int row = blockIdx.x * blockDim.x + threadIdx.x;
    const float a = alpha[0];
    const float b = beta[0];
    const float mn = key2f(ws[0]);
    const float mx = key2f(ws[1]);
    const float denom = mx - mn;

    const float4* __restrict__ xin = (const float4*)(in + (size_t)row * NCOL);
    float4* __restrict__ op = (float4*)(out + (size_t)row * NCOL);

    float w = 1.0f;
    // register prefetch pipeline: next load issued ~8 steps ahead
    float4 b0 = xin[0];
    float4 b1 = xin[1];
    for (int i = 0; i < NV4; ++i) {
        float4 x4 = b0;
        b0 = b1;
        if (i + 2 < NV4) b1 = xin[i + 2];
        float4 ov;
        ov.x = w;                                            // w_{4i}
        w = (w + a / w) - b * ((x4.x - mn) / denom); ov.y = w;  // w_{4i+1}
        w = (w + a / w) - b * ((x4.y - mn) / denom); ov.z = w;  // w_{4i+2}
        w = (w + a / w) - b * ((x4.z - mn) / denom); ov.w = w;  // w_{4i+3}
        w = (w + a / w) - b * ((x4.w - mn) / denom);            // carry w_{4i+4}
        op[i] = ov;  // last iter: x[511] step computed but discarded (matches ref)
    }
}

extern "C" void kernel_launch(void* const* d_in, const int* in_sizes, int n_in,
                              void* d_out, int out_size, void* d_ws, size_t ws_size,
                              hipStream_t stream) {
    const float* in    = (const float*)d_in[0];
    const float* alpha = (const float*)d_in[1];
    const float* beta  = (const float*)d_in[2];
    float* out = (float*)d_out;
    unsigned* ws = (unsigned*)d_ws;

    const int n_elem = in_sizes[0];       // 67108864
    const int n4 = n_elem / 4;

    hipLaunchKernelGGL(init_ws_kernel, dim3(1), dim3(1), 0, stream, ws);
    hipLaunchKernelGGL(minmax_kernel, dim3(2048), dim3(256), 0, stream,
                       (const float4*)in, ws, n4);
    hipLaunchKernelGGL(recur_kernel, dim3(ROWS / 256), dim3(256), 0, stream,
                       in, alpha, beta, ws, out);
}

// Round 2
// 854.387 us; speedup vs baseline: 1.0342x; 1.0342x over previous
//
#include <hip/hip_runtime.h>

// l=32, m=4096, n=512 fp32. Rows (131072) independent; n strictly sequential.
//   x = (input - min) / (max - min);  w[0]=1; w[k] = w[k-1] + a/w[k-1] - b*x[k-1]
// NUMERICS: recurrence is chaotic (absmax 192 vs threshold 233) — keep the
// exact expression ((w + a/w) - b*((x-mn)/denom)), IEEE div, contract off.
// R1 fix: R0's per-lane row walk gave 3.7x HBM amplification (1.9 GB vs 512 MB
// ideal). Stage 64-row x 32-col tiles through LDS: coalesced global phases,
// per-thread row consumption from LDS (pad 33 -> <=2-way bank alias, free).

#define ROWS 131072
#define NCOL 512
#define BROWS 64          // rows per (single-wave) block
#define TCOLS 32          // tile width in floats
#define NTILES (NCOL / TCOLS)
#define LDS_STRIDE 33     // +1 pad: bank = (row + col) % 32 -> 2-way max

__device__ __forceinline__ unsigned f2key(float f) {
    unsigned u = __float_as_uint(f);
    return (u & 0x80000000u) ? ~u : (u | 0x80000000u);  // monotone float->uint
}
__device__ __forceinline__ float key2f(unsigned k) {
    unsigned u = (k & 0x80000000u) ? (k & 0x7fffffffu) : ~k;
    return __uint_as_float(u);
}

__global__ void init_ws_kernel(unsigned* ws) {
    ws[0] = 0xFFFFFFFFu;  // min key accumulator
    ws[1] = 0u;           // max key accumulator
}

__global__ __launch_bounds__(256) void minmax_kernel(
        const float4* __restrict__ in, unsigned* __restrict__ ws, int n4) {
    unsigned mnk = 0xFFFFFFFFu, mxk = 0u;
    int idx = blockIdx.x * blockDim.x + threadIdx.x;
    int stride = gridDim.x * blockDim.x;
    for (int i = idx; i < n4; i += stride) {
        float4 v = in[i];
        unsigned k0 = f2key(v.x), k1 = f2key(v.y), k2 = f2key(v.z), k3 = f2key(v.w);
        mnk = min(mnk, min(min(k0, k1), min(k2, k3)));
        mxk = max(mxk, max(max(k0, k1), max(k2, k3)));
    }
    for (int off = 32; off; off >>= 1) {
        mnk = min(mnk, (unsigned)__shfl_down((int)mnk, off));
        mxk = max(mxk, (unsigned)__shfl_down((int)mxk, off));
    }
    if ((threadIdx.x & 63) == 0) {
        atomicMin(&ws[0], mnk);
        atomicMax(&ws[1], mxk);
    }
}

__global__ __launch_bounds__(64) void recur_kernel(
        const float* __restrict__ in,
        const float* __restrict__ alpha,
        const float* __restrict__ beta,
        const unsigned* __restrict__ ws,
        float* __restrict__ out) {
    #pragma clang fp contract(off)   // bit-match numpy: no fma fusion
    __shared__ float lds[BROWS * LDS_STRIDE];   // 8448 B -> 8 blocks/CU resident

    const int tid = threadIdx.x;
    const int r0 = blockIdx.x * BROWS;
    const float a = alpha[0];
    const float b = beta[0];
    const float mn = key2f(ws[0]);
    const float mx = key2f(ws[1]);
    const float denom = mx - mn;

    const float4* __restrict__ in4 = (const float4*)in;
    float4* __restrict__ out4 = (float4*)out;

    float w = 1.0f;
    for (int t = 0; t < NTILES; ++t) {
        // --- cooperative coalesced load: 8 float4/thread, lanes 0..7 cover one
        // 128B row segment (full cache lines) ---
        #pragma unroll
        for (int p = 0; p < 8; ++p) {
            int q = tid + p * 64;          // 0..511 linear float4 id in tile
            int row = q >> 3;              // 0..63
            int c4 = q & 7;                // 0..7
            float4 v = in4[(size_t)(r0 + row) * (NCOL / 4) + t * (TCOLS / 4) + c4];
            float* dst = &lds[row * LDS_STRIDE + c4 * 4];
            dst[0] = v.x; dst[1] = v.y; dst[2] = v.z; dst[3] = v.w;
        }
        __syncthreads();

        // --- per-thread: consume own LDS row, overwrite in place with outputs.
        // out[k] = w_k (pre-update w), then w = f(w, x[k]). ---
        float* myrow = &lds[tid * LDS_STRIDE];
        #pragma unroll
        for (int c = 0; c < TCOLS; ++c) {
            float x = myrow[c];
            float ov = w;
            w = (w + a / w) - b * ((x - mn) / denom);
            myrow[c] = ov;
        }
        __syncthreads();

        // --- cooperative coalesced store ---
        #pragma unroll
        for (int p = 0; p < 8; ++p) {
            int q = tid + p * 64;
            int row = q >> 3;
            int c4 = q & 7;
            const float* src = &lds[row * LDS_STRIDE + c4 * 4];
            float4 v;
            v.x = src[0]; v.y = src[1]; v.z = src[2]; v.w = src[3];
            out4[(size_t)(r0 + row) * (NCOL / 4) + t * (TCOLS / 4) + c4] = v;
        }
        __syncthreads();
    }
}

extern "C" void kernel_launch(void* const* d_in, const int* in_sizes, int n_in,
                              void* d_out, int out_size, void* d_ws, size_t ws_size,
                              hipStream_t stream) {
    const float* in    = (const float*)d_in[0];
    const float* alpha = (const float*)d_in[1];
    const float* beta  = (const float*)d_in[2];
    float* out = (float*)d_out;
    unsigned* ws = (unsigned*)d_ws;

    const int n_elem = in_sizes[0];   // 67108864
    const int n4 = n_elem / 4;

    hipLaunchKernelGGL(init_ws_kernel, dim3(1), dim3(1), 0, stream, ws);
    hipLaunchKernelGGL(minmax_kernel, dim3(4096), dim3(256), 0, stream,
                       (const float4*)in, ws, n4);
    hipLaunchKernelGGL(recur_kernel, dim3(ROWS / BROWS), dim3(64), 0, stream,
                       in, alpha, beta, ws, out);
}